// Round 4
// baseline (717.788 us; speedup 1.0000x reference)
//
#include <hip/hip_runtime.h>

#define N_NODES 100000
#define N_EDGES 1600000
#define H 128

// ---------------- CSR build ----------------

__global__ void zero_ints(int* __restrict__ p, int n) {
    int i = blockIdx.x * blockDim.x + threadIdx.x;
    if (i < n) p[i] = 0;
}

__global__ void count_deg(const int* __restrict__ dst, int* __restrict__ deg, int e) {
    int i = blockIdx.x * blockDim.x + threadIdx.x;
    if (i < e) atomicAdd(&deg[dst[i]], 1);
}

// per-1024-block exclusive scan; bsums[b] = block total
__global__ void scan_blocks(const int* __restrict__ deg, int* __restrict__ rowstart,
                            int* __restrict__ bsums, int n) {
    __shared__ int s[1024];
    int t = threadIdx.x;
    int i = blockIdx.x * 1024 + t;
    int v = (i < n) ? deg[i] : 0;
    s[t] = v;
    __syncthreads();
    for (int off = 1; off < 1024; off <<= 1) {
        int add = (t >= off) ? s[t - off] : 0;
        __syncthreads();
        s[t] += add;
        __syncthreads();
    }
    if (i < n) rowstart[i] = s[t] - v;   // exclusive
    if (t == 1023) bsums[blockIdx.x] = s[t];
}

__global__ void scan_sums(const int* __restrict__ bsums, int* __restrict__ boffs, int nb) {
    __shared__ int s[128];
    int t = threadIdx.x;
    int v = (t < nb) ? bsums[t] : 0;
    s[t] = v;
    __syncthreads();
    for (int off = 1; off < 128; off <<= 1) {
        int add = (t >= off) ? s[t - off] : 0;
        __syncthreads();
        s[t] += add;
        __syncthreads();
    }
    if (t < nb) boffs[t] = s[t] - v;     // exclusive
}

__global__ void add_offsets(int* __restrict__ rowstart, const int* __restrict__ boffs, int n) {
    int i = blockIdx.x * blockDim.x + threadIdx.x;
    if (i < n) rowstart[i] += boffs[i >> 10];
}

__global__ void fill_csr(const int* __restrict__ src, const int* __restrict__ dst,
                         const int* __restrict__ rowstart, int* __restrict__ cursor,
                         int* __restrict__ csr, int e) {
    int i = blockIdx.x * blockDim.x + threadIdx.x;
    if (i < e) {
        int d = dst[i];
        int slot = atomicAdd(&cursor[d], 1);
        csr[rowstart[d] + slot] = src[i];
    }
}

// ---------------- Aggregation: one wave per node, gather ----------------

__global__ __launch_bounds__(256) void agg(
    const float* __restrict__ xin, const int* __restrict__ csr,
    const int* __restrict__ rowstart, const int* __restrict__ deg,
    float* __restrict__ mout)
{
    int w = (blockIdx.x * blockDim.x + threadIdx.x) >> 6;
    if (w >= N_NODES) return;
    int lane = threadIdx.x & 63;
    int beg = rowstart[w];
    int d = deg[w];
    float2 acc = make_float2(0.f, 0.f);
    const float* base = xin + (lane << 1);
    for (int i = 0; i < d; ++i) {
        int s = csr[beg + i];
        const float2 v = *(const float2*)(base + ((size_t)s << 7));
        acc.x += v.x;
        acc.y += v.y;
    }
    float inv = 1.f / (float)(d > 0 ? d : 1);
    float2 o;
    o.x = acc.x * inv;
    o.y = acc.y * inv;
    *(float2*)(mout + ((size_t)w << 7) + (lane << 1)) = o;
}

// ---------------- Fused dual-GEMM: out = act(A@Wl.T + bl + X@Wr.T) ----------------
// Block: 256 threads -> 32 rows x 128 cols tile. Thread = 4 rows x 4 cols.
// K staged in tiles of 32 in LDS. Safe for X==out (rows read before written,
// block-local rows only).

#define RT 32
#define KT 32

__global__ __launch_bounds__(256) void gemm_fused(
    const float* __restrict__ A, const float* __restrict__ X,
    const float* __restrict__ Wl, const float* __restrict__ bl,
    const float* __restrict__ Wr, float* __restrict__ out, int relu)
{
    __shared__ float sWl[KT][132];    // [kk][j], pad 132 -> conflict-free both sides
    __shared__ float sWr[KT][132];
    __shared__ float sM[RT][KT + 4];  // [r][kk], stride 36 keeps float4 alignment
    __shared__ float sX[RT][KT + 4];

    const int t = threadIdx.x;
    const int jc = (t & 31) << 2;   // col base 0..124
    const int rg = (t >> 5) << 2;   // row base 0..28
    const int row0 = blockIdx.x * RT;

    float acc[4][4];
#pragma unroll
    for (int r = 0; r < 4; ++r)
#pragma unroll
        for (int c = 0; c < 4; ++c) acc[r][c] = 0.f;

    for (int k0 = 0; k0 < H; k0 += KT) {
        __syncthreads();
        // stage W tiles (128 j x 32 kk each)
#pragma unroll
        for (int it = 0; it < 16; ++it) {
            int f = it * 256 + t;
            int kk = f & (KT - 1);
            int jw = f >> 5;
            sWl[kk][jw] = Wl[jw * H + k0 + kk];
            sWr[kk][jw] = Wr[jw * H + k0 + kk];
        }
        // stage row tiles (32 r x 32 kk each)
#pragma unroll
        for (int it = 0; it < 4; ++it) {
            int f = it * 256 + t;
            int kk = f & (KT - 1);
            int r = f >> 5;
            sM[r][kk] = A[(size_t)(row0 + r) * H + k0 + kk];
            sX[r][kk] = X[(size_t)(row0 + r) * H + k0 + kk];
        }
        __syncthreads();
#pragma unroll 4
        for (int kk = 0; kk < KT; ++kk) {
            float4 wl = *(float4*)&sWl[kk][jc];
            float4 wr = *(float4*)&sWr[kk][jc];
#pragma unroll
            for (int r = 0; r < 4; ++r) {
                float m = sM[rg + r][kk];
                float xv = sX[rg + r][kk];
                acc[r][0] += m * wl.x; acc[r][0] += xv * wr.x;
                acc[r][1] += m * wl.y; acc[r][1] += xv * wr.y;
                acc[r][2] += m * wl.z; acc[r][2] += xv * wr.z;
                acc[r][3] += m * wl.w; acc[r][3] += xv * wr.w;
            }
        }
    }

    float4 bv = *(const float4*)(bl + jc);
#pragma unroll
    for (int r = 0; r < 4; ++r) {
        float4 o;
        o.x = acc[r][0] + bv.x;
        o.y = acc[r][1] + bv.y;
        o.z = acc[r][2] + bv.z;
        o.w = acc[r][3] + bv.w;
        if (relu) {
            o.x = fmaxf(o.x, 0.f); o.y = fmaxf(o.y, 0.f);
            o.z = fmaxf(o.z, 0.f); o.w = fmaxf(o.w, 0.f);
        }
        *(float4*)(out + (size_t)(row0 + rg + r) * H + jc) = o;
    }
}

// ---------------- launch ----------------

extern "C" void kernel_launch(void* const* d_in, const int* in_sizes, int n_in,
                              void* d_out, int out_size, void* d_ws, size_t ws_size,
                              hipStream_t stream) {
    const float* x   = (const float*)d_in[0];
    const int*   ei  = (const int*)d_in[1];
    const float* W1l = (const float*)d_in[2];
    const float* b1l = (const float*)d_in[3];
    const float* W1r = (const float*)d_in[4];
    const float* W2l = (const float*)d_in[5];
    const float* b2l = (const float*)d_in[6];
    const float* W2r = (const float*)d_in[7];

    const int* src = ei;             // edge_index[0]
    const int* dst = ei + N_EDGES;   // edge_index[1]

    // workspace layout
    float* mean   = (float*)d_ws;                       // N*H floats (51.2MB)
    int* deg      = (int*)(mean + (size_t)N_NODES * H); // N
    int* rowstart = deg + N_NODES;                      // N
    int* cursor   = rowstart + N_NODES;                 // N
    int* csr      = cursor + N_NODES;                   // E
    int* bsums    = csr + N_EDGES;                      // 128
    int* boffs    = bsums + 128;                        // 128

    float* h1  = (float*)d_out;  // layer-1 activations live in d_out
    float* out = (float*)d_out;

    const int nb = (N_NODES + 1023) / 1024;  // 98 scan blocks

    // CSR build (deg/rowstart/cursor zeroed together: contiguous 3N ints)
    zero_ints<<<(3 * N_NODES + 255) / 256, 256, 0, stream>>>(deg, 3 * N_NODES);
    count_deg<<<(N_EDGES + 255) / 256, 256, 0, stream>>>(dst, deg, N_EDGES);
    scan_blocks<<<nb, 1024, 0, stream>>>(deg, rowstart, bsums, N_NODES);
    scan_sums<<<1, 128, 0, stream>>>(bsums, boffs, nb);
    add_offsets<<<(N_NODES + 255) / 256, 256, 0, stream>>>(rowstart, boffs, N_NODES);
    fill_csr<<<(N_EDGES + 255) / 256, 256, 0, stream>>>(src, dst, rowstart, cursor, csr, N_EDGES);

    // layer 1
    agg<<<(N_NODES + 3) / 4, 256, 0, stream>>>(x, csr, rowstart, deg, mean);
    gemm_fused<<<N_NODES / RT, 256, 0, stream>>>(mean, x, W1l, b1l, W1r, h1, 1);

    // layer 2 (reads h1 from d_out, writes d_out; block-local row reuse is safe)
    agg<<<(N_NODES + 3) / 4, 256, 0, stream>>>(h1, csr, rowstart, deg, mean);
    gemm_fused<<<N_NODES / RT, 256, 0, stream>>>(mean, h1, W2l, b2l, W2r, out, 0);
}

// Round 5
// 613.009 us; speedup vs baseline: 1.1709x; 1.1709x over previous
//
#include <hip/hip_runtime.h>

#define N_NODES 100000
#define N_EDGES 1600000
#define H 128

// ---------------- CSR build ----------------

__global__ void zero_ints(int* __restrict__ p, int n) {
    int i = blockIdx.x * blockDim.x + threadIdx.x;
    if (i < n) p[i] = 0;
}

__global__ void count_deg(const int* __restrict__ dst, int* __restrict__ deg, int e) {
    int i = blockIdx.x * blockDim.x + threadIdx.x;
    if (i < e) atomicAdd(&deg[dst[i]], 1);
}

// per-1024-block exclusive scan; bsums[b] = block total
__global__ void scan_blocks(const int* __restrict__ deg, int* __restrict__ rowstart,
                            int* __restrict__ bsums, int n) {
    __shared__ int s[1024];
    int t = threadIdx.x;
    int i = blockIdx.x * 1024 + t;
    int v = (i < n) ? deg[i] : 0;
    s[t] = v;
    __syncthreads();
    for (int off = 1; off < 1024; off <<= 1) {
        int add = (t >= off) ? s[t - off] : 0;
        __syncthreads();
        s[t] += add;
        __syncthreads();
    }
    if (i < n) rowstart[i] = s[t] - v;   // exclusive
    if (t == 1023) bsums[blockIdx.x] = s[t];
}

__global__ void scan_sums(const int* __restrict__ bsums, int* __restrict__ boffs, int nb) {
    __shared__ int s[128];
    int t = threadIdx.x;
    int v = (t < nb) ? bsums[t] : 0;
    s[t] = v;
    __syncthreads();
    for (int off = 1; off < 128; off <<= 1) {
        int add = (t >= off) ? s[t - off] : 0;
        __syncthreads();
        s[t] += add;
        __syncthreads();
    }
    if (t < nb) boffs[t] = s[t] - v;     // exclusive
}

__global__ void add_offsets(int* __restrict__ rowstart, const int* __restrict__ boffs, int n) {
    int i = blockIdx.x * blockDim.x + threadIdx.x;
    if (i < n) rowstart[i] += boffs[i >> 10];
}

__global__ void fill_csr(const int* __restrict__ src, const int* __restrict__ dst,
                         const int* __restrict__ rowstart, int* __restrict__ cursor,
                         int* __restrict__ csr, int e) {
    int i = blockIdx.x * blockDim.x + threadIdx.x;
    if (i < e) {
        int d = dst[i];
        int slot = atomicAdd(&cursor[d], 1);
        csr[rowstart[d] + slot] = src[i];
    }
}

// ---------------- Aggregation: one wave per node, 8-wide MLP gather ----------------
// Latency-bound fix (R4 profile: VALUBusy 13%, hbm 31%, occupancy 75%):
// batch 8 independent row loads in flight; scalar (wave-uniform) index loads.

__global__ __launch_bounds__(256) void agg(
    const float* __restrict__ xin, const int* __restrict__ csr,
    const int* __restrict__ rowstart, const int* __restrict__ deg,
    float* __restrict__ mout)
{
    int w = (blockIdx.x * blockDim.x + threadIdx.x) >> 6;
    if (w >= N_NODES) return;
    int lane = threadIdx.x & 63;
    int beg = __builtin_amdgcn_readfirstlane(rowstart[w]);
    int d   = __builtin_amdgcn_readfirstlane(deg[w]);
    const float* base = xin + (lane << 1);

    float2 a[8];
#pragma unroll
    for (int u = 0; u < 8; ++u) a[u] = make_float2(0.f, 0.f);

    int i = 0;
    for (; i + 8 <= d; i += 8) {
        int s[8];
#pragma unroll
        for (int u = 0; u < 8; ++u) s[u] = csr[beg + i + u];
#pragma unroll
        for (int u = 0; u < 8; ++u) {
            float2 v = *(const float2*)(base + ((size_t)s[u] << 7));
            a[u].x += v.x;
            a[u].y += v.y;
        }
    }
    if (i < d) {
        int cnt = d - i;  // 1..7, wave-uniform
        int s[8];
#pragma unroll
        for (int u = 0; u < 8; ++u) s[u] = csr[beg + i + ((u < cnt) ? u : 0)];
#pragma unroll
        for (int u = 0; u < 8; ++u) {
            float2 v = *(const float2*)(base + ((size_t)s[u] << 7));
            if (u < cnt) {  // wave-uniform predicate
                a[u].x += v.x;
                a[u].y += v.y;
            }
        }
    }

    // tree sum of 8 accumulators
#pragma unroll
    for (int u = 0; u < 4; ++u) { a[u].x += a[u + 4].x; a[u].y += a[u + 4].y; }
    a[0].x += a[2].x; a[0].y += a[2].y;
    a[1].x += a[3].x; a[1].y += a[3].y;
    a[0].x += a[1].x; a[0].y += a[1].y;

    float inv = 1.f / (float)(d > 0 ? d : 1);
    float2 o;
    o.x = a[0].x * inv;
    o.y = a[0].y * inv;
    *(float2*)(mout + ((size_t)w << 7) + (lane << 1)) = o;
}

// ---------------- Fused dual-GEMM: out = act(A@Wl.T + bl + X@Wr.T) ----------------
// Block: 256 threads -> 32 rows x 128 cols tile. Thread = 4 rows x 4 cols.
// K staged in tiles of 32 in LDS. Safe for X==out (rows read before written,
// block-local rows only).

#define RT 32
#define KT 32

__global__ __launch_bounds__(256) void gemm_fused(
    const float* __restrict__ A, const float* __restrict__ X,
    const float* __restrict__ Wl, const float* __restrict__ bl,
    const float* __restrict__ Wr, float* __restrict__ out, int relu)
{
    __shared__ float sWl[KT][132];    // [kk][j], pad 132 -> conflict-free both sides
    __shared__ float sWr[KT][132];
    __shared__ float sM[RT][KT + 4];  // [r][kk], stride 36 keeps float4 alignment
    __shared__ float sX[RT][KT + 4];

    const int t = threadIdx.x;
    const int jc = (t & 31) << 2;   // col base 0..124
    const int rg = (t >> 5) << 2;   // row base 0..28
    const int row0 = blockIdx.x * RT;

    float acc[4][4];
#pragma unroll
    for (int r = 0; r < 4; ++r)
#pragma unroll
        for (int c = 0; c < 4; ++c) acc[r][c] = 0.f;

    for (int k0 = 0; k0 < H; k0 += KT) {
        __syncthreads();
        // stage W tiles (128 j x 32 kk each)
#pragma unroll
        for (int it = 0; it < 16; ++it) {
            int f = it * 256 + t;
            int kk = f & (KT - 1);
            int jw = f >> 5;
            sWl[kk][jw] = Wl[jw * H + k0 + kk];
            sWr[kk][jw] = Wr[jw * H + k0 + kk];
        }
        // stage row tiles (32 r x 32 kk each)
#pragma unroll
        for (int it = 0; it < 4; ++it) {
            int f = it * 256 + t;
            int kk = f & (KT - 1);
            int r = f >> 5;
            sM[r][kk] = A[(size_t)(row0 + r) * H + k0 + kk];
            sX[r][kk] = X[(size_t)(row0 + r) * H + k0 + kk];
        }
        __syncthreads();
#pragma unroll 4
        for (int kk = 0; kk < KT; ++kk) {
            float4 wl = *(float4*)&sWl[kk][jc];
            float4 wr = *(float4*)&sWr[kk][jc];
#pragma unroll
            for (int r = 0; r < 4; ++r) {
                float m = sM[rg + r][kk];
                float xv = sX[rg + r][kk];
                acc[r][0] += m * wl.x; acc[r][0] += xv * wr.x;
                acc[r][1] += m * wl.y; acc[r][1] += xv * wr.y;
                acc[r][2] += m * wl.z; acc[r][2] += xv * wr.z;
                acc[r][3] += m * wl.w; acc[r][3] += xv * wr.w;
            }
        }
    }

    float4 bv = *(const float4*)(bl + jc);
#pragma unroll
    for (int r = 0; r < 4; ++r) {
        float4 o;
        o.x = acc[r][0] + bv.x;
        o.y = acc[r][1] + bv.y;
        o.z = acc[r][2] + bv.z;
        o.w = acc[r][3] + bv.w;
        if (relu) {
            o.x = fmaxf(o.x, 0.f); o.y = fmaxf(o.y, 0.f);
            o.z = fmaxf(o.z, 0.f); o.w = fmaxf(o.w, 0.f);
        }
        *(float4*)(out + (size_t)(row0 + rg + r) * H + jc) = o;
    }
}

// ---------------- launch ----------------

extern "C" void kernel_launch(void* const* d_in, const int* in_sizes, int n_in,
                              void* d_out, int out_size, void* d_ws, size_t ws_size,
                              hipStream_t stream) {
    const float* x   = (const float*)d_in[0];
    const int*   ei  = (const int*)d_in[1];
    const float* W1l = (const float*)d_in[2];
    const float* b1l = (const float*)d_in[3];
    const float* W1r = (const float*)d_in[4];
    const float* W2l = (const float*)d_in[5];
    const float* b2l = (const float*)d_in[6];
    const float* W2r = (const float*)d_in[7];

    const int* src = ei;             // edge_index[0]
    const int* dst = ei + N_EDGES;   // edge_index[1]

    // workspace layout
    float* mean   = (float*)d_ws;                       // N*H floats (51.2MB)
    int* deg      = (int*)(mean + (size_t)N_NODES * H); // N
    int* rowstart = deg + N_NODES;                      // N
    int* cursor   = rowstart + N_NODES;                 // N
    int* csr      = cursor + N_NODES;                   // E
    int* bsums    = csr + N_EDGES;                      // 128
    int* boffs    = bsums + 128;                        // 128

    float* h1  = (float*)d_out;  // layer-1 activations live in d_out
    float* out = (float*)d_out;

    const int nb = (N_NODES + 1023) / 1024;  // 98 scan blocks

    // CSR build (deg/rowstart/cursor zeroed together: contiguous 3N ints)
    zero_ints<<<(3 * N_NODES + 255) / 256, 256, 0, stream>>>(deg, 3 * N_NODES);
    count_deg<<<(N_EDGES + 255) / 256, 256, 0, stream>>>(dst, deg, N_EDGES);
    scan_blocks<<<nb, 1024, 0, stream>>>(deg, rowstart, bsums, N_NODES);
    scan_sums<<<1, 128, 0, stream>>>(bsums, boffs, nb);
    add_offsets<<<(N_NODES + 255) / 256, 256, 0, stream>>>(rowstart, boffs, N_NODES);
    fill_csr<<<(N_EDGES + 255) / 256, 256, 0, stream>>>(src, dst, rowstart, cursor, csr, N_EDGES);

    // layer 1
    agg<<<(N_NODES + 3) / 4, 256, 0, stream>>>(x, csr, rowstart, deg, mean);
    gemm_fused<<<N_NODES / RT, 256, 0, stream>>>(mean, x, W1l, b1l, W1r, h1, 1);

    // layer 2 (reads h1 from d_out, writes d_out; block-local row reuse is safe)
    agg<<<(N_NODES + 3) / 4, 256, 0, stream>>>(h1, csr, rowstart, deg, mean);
    gemm_fused<<<N_NODES / RT, 256, 0, stream>>>(mean, h1, W2l, b2l, W2r, out, 0);
}

// Round 6
// 446.990 us; speedup vs baseline: 1.6058x; 1.3714x over previous
//
#include <hip/hip_runtime.h>

#define N_NODES 100000
#define N_EDGES 1600000
#define H 128

typedef unsigned short u16;
typedef unsigned int u32;
typedef short bf16x8 __attribute__((ext_vector_type(8)));
typedef float f32x4 __attribute__((ext_vector_type(4)));

static __device__ __forceinline__ u16 f2bf(float f) {  // RNE float->bf16
    u32 u = __float_as_uint(f);
    u += 0x7fffu + ((u >> 16) & 1u);
    return (u16)(u >> 16);
}

// ---------------- CSR build ----------------

__global__ void zero_ints(int* __restrict__ p, int n) {
    int i = blockIdx.x * blockDim.x + threadIdx.x;
    if (i < n) p[i] = 0;
}

__global__ void count_deg(const int* __restrict__ dst, int* __restrict__ deg, int e) {
    int i = blockIdx.x * blockDim.x + threadIdx.x;
    if (i < e) atomicAdd(&deg[dst[i]], 1);
}

__global__ void scan_blocks(const int* __restrict__ deg, int* __restrict__ rowstart,
                            int* __restrict__ bsums, int n) {
    __shared__ int s[1024];
    int t = threadIdx.x;
    int i = blockIdx.x * 1024 + t;
    int v = (i < n) ? deg[i] : 0;
    s[t] = v;
    __syncthreads();
    for (int off = 1; off < 1024; off <<= 1) {
        int add = (t >= off) ? s[t - off] : 0;
        __syncthreads();
        s[t] += add;
        __syncthreads();
    }
    if (i < n) rowstart[i] = s[t] - v;   // exclusive
    if (t == 1023) bsums[blockIdx.x] = s[t];
}

__global__ void scan_sums(const int* __restrict__ bsums, int* __restrict__ boffs, int nb) {
    __shared__ int s[128];
    int t = threadIdx.x;
    int v = (t < nb) ? bsums[t] : 0;
    s[t] = v;
    __syncthreads();
    for (int off = 1; off < 128; off <<= 1) {
        int add = (t >= off) ? s[t - off] : 0;
        __syncthreads();
        s[t] += add;
        __syncthreads();
    }
    if (t < nb) boffs[t] = s[t] - v;     // exclusive
}

__global__ void add_offsets(int* __restrict__ rowstart, const int* __restrict__ boffs, int n) {
    int i = blockIdx.x * blockDim.x + threadIdx.x;
    if (i < n) rowstart[i] += boffs[i >> 10];
}

__global__ void fill_csr(const int* __restrict__ src, const int* __restrict__ dst,
                         const int* __restrict__ rowstart, int* __restrict__ cursor,
                         int* __restrict__ csr, int e) {
    int i = blockIdx.x * blockDim.x + threadIdx.x;
    if (i < e) {
        int d = dst[i];
        int slot = atomicAdd(&cursor[d], 1);
        csr[rowstart[d] + slot] = src[i];
    }
}

// ---------------- casts ----------------

__global__ __launch_bounds__(256) void cast_x(const float* __restrict__ in,
                                              u16* __restrict__ out) {
    int i = blockIdx.x * 256 + threadIdx.x;   // 1.6M threads x 8 elems
    const float4 v0 = *(const float4*)(in + (size_t)i * 8);
    const float4 v1 = *(const float4*)(in + (size_t)i * 8 + 4);
    u16 o[8];
    o[0]=f2bf(v0.x); o[1]=f2bf(v0.y); o[2]=f2bf(v0.z); o[3]=f2bf(v0.w);
    o[4]=f2bf(v1.x); o[5]=f2bf(v1.y); o[6]=f2bf(v1.z); o[7]=f2bf(v1.w);
    *(bf16x8*)(out + (size_t)i * 8) = *(bf16x8*)o;
}

__global__ __launch_bounds__(256) void cast_w(const float* __restrict__ w1l,
                                              const float* __restrict__ w1r,
                                              const float* __restrict__ w2l,
                                              const float* __restrict__ w2r,
                                              u16* __restrict__ out) {
    int i = blockIdx.x * 256 + threadIdx.x;   // 65536 threads
    int mat = i >> 14, idx = i & 16383;
    const float* s = (mat == 0) ? w1l : (mat == 1) ? w1r : (mat == 2) ? w2l : w2r;
    out[i] = f2bf(s[idx]);
}

// ---------------- Aggregation: wave/node, 8-wide MLP, bf16 in/out ----------------

__global__ __launch_bounds__(256) void agg_bf16(
    const u16* __restrict__ xin, const int* __restrict__ csr,
    const int* __restrict__ rowstart, const int* __restrict__ deg,
    u16* __restrict__ mout)
{
    int w = (blockIdx.x * blockDim.x + threadIdx.x) >> 6;
    if (w >= N_NODES) return;
    int lane = threadIdx.x & 63;
    int beg = __builtin_amdgcn_readfirstlane(rowstart[w]);
    int d   = __builtin_amdgcn_readfirstlane(deg[w]);
    const u16* base = xin + (lane << 1);    // 2 bf16 (4B) per lane, row=256B

    float ax[8], ay[8];
#pragma unroll
    for (int u = 0; u < 8; ++u) { ax[u] = 0.f; ay[u] = 0.f; }

    int i = 0;
    for (; i + 8 <= d; i += 8) {
        int s[8];
#pragma unroll
        for (int u = 0; u < 8; ++u) s[u] = csr[beg + i + u];
#pragma unroll
        for (int u = 0; u < 8; ++u) {
            u32 v = *(const u32*)(base + ((size_t)s[u] << 7));
            ax[u] += __uint_as_float(v << 16);
            ay[u] += __uint_as_float(v & 0xffff0000u);
        }
    }
    if (i < d) {
        int cnt = d - i;  // 1..7, wave-uniform
        int s[8];
#pragma unroll
        for (int u = 0; u < 8; ++u) s[u] = csr[beg + i + ((u < cnt) ? u : 0)];
#pragma unroll
        for (int u = 0; u < 8; ++u) {
            u32 v = *(const u32*)(base + ((size_t)s[u] << 7));
            if (u < cnt) {
                ax[u] += __uint_as_float(v << 16);
                ay[u] += __uint_as_float(v & 0xffff0000u);
            }
        }
    }

#pragma unroll
    for (int u = 0; u < 4; ++u) { ax[u] += ax[u + 4]; ay[u] += ay[u + 4]; }
    ax[0] += ax[2]; ay[0] += ay[2];
    ax[1] += ax[3]; ay[1] += ay[3];
    ax[0] += ax[1]; ay[0] += ay[1];

    float inv = 1.f / (float)(d > 0 ? d : 1);
    u32 packed = (u32)f2bf(ax[0] * inv) | ((u32)f2bf(ay[0] * inv) << 16);
    *(u32*)(mout + ((size_t)w << 7) + (lane << 1)) = packed;
}

// ---------------- MFMA dual-GEMM: out = act(A@Wl.T + bl + X@Wr.T) ----------------
// No LDS. 4 waves/block, wave = 16 rows x 128 cols (8 col-tiles of 16).
// mfma_f32_16x16x32_bf16: A lane l holds In[m0+(l&15)][k0*32+(l>>4)*8+j] (16B contig);
// B lane l holds W[n0+(l&15)][k0*32+(l>>4)*8+j] (16B contig, since B[k][n]=W[n][k]).
// C/D (m89-verified): col=lane&15, row=(lane>>4)*4+reg.
// Safe for in-place X==out (bf16 mode): each wave reads only its own 16 rows
// (all loads issued before stores; other blocks never touch these rows).

__global__ __launch_bounds__(256) void gemm_mfma(
    const u16* __restrict__ Ab, const u16* __restrict__ Xb,
    const u16* __restrict__ Wlb, const float* __restrict__ bl,
    const u16* __restrict__ Wrb, void* __restrict__ outp, int relu_bf16)
{
    const int wv = threadIdx.x >> 6;
    const int l  = threadIdx.x & 63;
    const int m0 = blockIdx.x * 64 + wv * 16;
    const int lr = l & 15;          // A-row / B-col / D-col within tile
    const int lq = l >> 4;          // 0..3 (k-slice / D-row group)

    int arow = m0 + lr;
    if (arow > N_NODES - 1) arow = N_NODES - 1;   // clamp loads; stores masked
    const u16* abase = Ab + (size_t)arow * H + lq * 8;
    const u16* xbase = Xb + (size_t)arow * H + lq * 8;
    const u16* wlbase = Wlb + (size_t)lr * H + lq * 8;
    const u16* wrbase = Wrb + (size_t)lr * H + lq * 8;

    f32x4 acc[8];
#pragma unroll
    for (int t = 0; t < 8; ++t) acc[t] = (f32x4)0.f;

#pragma unroll
    for (int k0 = 0; k0 < 4; ++k0) {
        bf16x8 af = *(const bf16x8*)(abase + k0 * 32);
        bf16x8 xf = *(const bf16x8*)(xbase + k0 * 32);
#pragma unroll
        for (int t = 0; t < 8; ++t) {
            bf16x8 wl = *(const bf16x8*)(wlbase + (size_t)t * 16 * H + k0 * 32);
            bf16x8 wr = *(const bf16x8*)(wrbase + (size_t)t * 16 * H + k0 * 32);
            acc[t] = __builtin_amdgcn_mfma_f32_16x16x32_bf16(af, wl, acc[t], 0, 0, 0);
            acc[t] = __builtin_amdgcn_mfma_f32_16x16x32_bf16(xf, wr, acc[t], 0, 0, 0);
        }
    }

    u16* outb = (u16*)outp;
    float* outf = (float*)outp;
#pragma unroll
    for (int t = 0; t < 8; ++t) {
        int n = t * 16 + lr;
        float bv = bl[n];
#pragma unroll
        for (int r = 0; r < 4; ++r) {
            int m = m0 + lq * 4 + r;
            if (m < N_NODES) {
                float v = acc[t][r] + bv;
                if (relu_bf16) {
                    outb[(size_t)m * H + n] = f2bf(fmaxf(v, 0.f));
                } else {
                    outf[(size_t)m * H + n] = v;
                }
            }
        }
    }
}

// ---------------- launch ----------------

extern "C" void kernel_launch(void* const* d_in, const int* in_sizes, int n_in,
                              void* d_out, int out_size, void* d_ws, size_t ws_size,
                              hipStream_t stream) {
    const float* x   = (const float*)d_in[0];
    const int*   ei  = (const int*)d_in[1];
    const float* W1l = (const float*)d_in[2];
    const float* b1l = (const float*)d_in[3];
    const float* W1r = (const float*)d_in[4];
    const float* W2l = (const float*)d_in[5];
    const float* b2l = (const float*)d_in[6];
    const float* W2r = (const float*)d_in[7];

    const int* src = ei;             // edge_index[0]
    const int* dst = ei + N_EDGES;   // edge_index[1]

    // workspace layout (58.8 MB total, same footprint as prior rounds)
    u16* xb       = (u16*)d_ws;                          // N*H bf16 (25.6MB); becomes h1b after gemm1
    u16* mb       = xb + (size_t)N_NODES * H;            // N*H bf16 (25.6MB)
    int* deg      = (int*)(mb + (size_t)N_NODES * H);    // N
    int* rowstart = deg + N_NODES;                       // N
    int* cursor   = rowstart + N_NODES;                  // N (dead after fill_csr -> holds bf16 weights)
    int* csr      = cursor + N_NODES;                    // E
    int* bsums    = csr + N_EDGES;                       // 128
    int* boffs    = bsums + 128;                         // 128
    u16* Wb       = (u16*)cursor;                        // 4 x 128*128 bf16 = 128KB (< 400KB)
    u16* W1lb = Wb;
    u16* W1rb = Wb + 16384;
    u16* W2lb = Wb + 32768;
    u16* W2rb = Wb + 49152;

    const int nb = (N_NODES + 1023) / 1024;  // 98 scan blocks

    // CSR build
    zero_ints<<<(3 * N_NODES + 255) / 256, 256, 0, stream>>>(deg, 3 * N_NODES);
    count_deg<<<(N_EDGES + 255) / 256, 256, 0, stream>>>(dst, deg, N_EDGES);
    scan_blocks<<<nb, 1024, 0, stream>>>(deg, rowstart, bsums, N_NODES);
    scan_sums<<<1, 128, 0, stream>>>(bsums, boffs, nb);
    add_offsets<<<(N_NODES + 255) / 256, 256, 0, stream>>>(rowstart, boffs, N_NODES);
    fill_csr<<<(N_EDGES + 255) / 256, 256, 0, stream>>>(src, dst, rowstart, cursor, csr, N_EDGES);

    // precasts (cast_w AFTER fill_csr: reuses cursor region)
    cast_w<<<65536 / 256, 256, 0, stream>>>(W1l, W1r, W2l, W2r, Wb);
    cast_x<<<(N_NODES * H / 8) / 256, 256, 0, stream>>>(x, xb);

    const int gemm_grid = (N_NODES + 63) / 64;

    // layer 1
    agg_bf16<<<(N_NODES + 3) / 4, 256, 0, stream>>>(xb, csr, rowstart, deg, mb);
    gemm_mfma<<<gemm_grid, 256, 0, stream>>>(mb, xb, W1lb, b1l, W1rb, xb, 1);  // h1b in-place over xb

    // layer 2
    agg_bf16<<<(N_NODES + 3) / 4, 256, 0, stream>>>(xb, csr, rowstart, deg, mb);
    gemm_mfma<<<gemm_grid, 256, 0, stream>>>(mb, xb, W2lb, b2l, W2rb, d_out, 0);
}

// Round 7
// 443.561 us; speedup vs baseline: 1.6182x; 1.0077x over previous
//
#include <hip/hip_runtime.h>

#define N_NODES 100000
#define N_EDGES 1600000
#define H 128

typedef unsigned short u16;
typedef unsigned int u32;
typedef short bf16x8 __attribute__((ext_vector_type(8)));
typedef float f32x4 __attribute__((ext_vector_type(4)));

static __device__ __forceinline__ u16 f2bf(float f) {  // RNE float->bf16
    u32 u = __float_as_uint(f);
    u += 0x7fffu + ((u >> 16) & 1u);
    return (u16)(u >> 16);
}

// ---------------- CSR build ----------------

__global__ void zero_ints(int* __restrict__ p, int n) {
    int i = blockIdx.x * blockDim.x + threadIdx.x;
    if (i < n) p[i] = 0;
}

__global__ void count_deg(const int* __restrict__ dst, int* __restrict__ deg, int e) {
    int i = blockIdx.x * blockDim.x + threadIdx.x;
    if (i < e) atomicAdd(&deg[dst[i]], 1);
}

__global__ void scan_blocks(const int* __restrict__ deg, int* __restrict__ rowstart,
                            int* __restrict__ bsums, int n) {
    __shared__ int s[1024];
    int t = threadIdx.x;
    int i = blockIdx.x * 1024 + t;
    int v = (i < n) ? deg[i] : 0;
    s[t] = v;
    __syncthreads();
    for (int off = 1; off < 1024; off <<= 1) {
        int add = (t >= off) ? s[t - off] : 0;
        __syncthreads();
        s[t] += add;
        __syncthreads();
    }
    if (i < n) rowstart[i] = s[t] - v;   // exclusive
    if (t == 1023) bsums[blockIdx.x] = s[t];
}

__global__ void scan_sums(const int* __restrict__ bsums, int* __restrict__ boffs, int nb) {
    __shared__ int s[128];
    int t = threadIdx.x;
    int v = (t < nb) ? bsums[t] : 0;
    s[t] = v;
    __syncthreads();
    for (int off = 1; off < 128; off <<= 1) {
        int add = (t >= off) ? s[t - off] : 0;
        __syncthreads();
        s[t] += add;
        __syncthreads();
    }
    if (t < nb) boffs[t] = s[t] - v;     // exclusive
}

__global__ void add_offsets(int* __restrict__ rowstart, const int* __restrict__ boffs, int n) {
    int i = blockIdx.x * blockDim.x + threadIdx.x;
    if (i < n) rowstart[i] += boffs[i >> 10];
}

__global__ void fill_csr(const int* __restrict__ src, const int* __restrict__ dst,
                         const int* __restrict__ rowstart, int* __restrict__ cursor,
                         int* __restrict__ csr, int e) {
    int i = blockIdx.x * blockDim.x + threadIdx.x;
    if (i < e) {
        int d = dst[i];
        int slot = atomicAdd(&cursor[d], 1);
        csr[rowstart[d] + slot] = src[i];
    }
}

// ---------------- casts ----------------

__global__ __launch_bounds__(256) void cast_x(const float* __restrict__ in,
                                              u16* __restrict__ out) {
    int i = blockIdx.x * 256 + threadIdx.x;   // 1.6M threads x 8 elems
    const float4 v0 = *(const float4*)(in + (size_t)i * 8);
    const float4 v1 = *(const float4*)(in + (size_t)i * 8 + 4);
    u16 o[8];
    o[0]=f2bf(v0.x); o[1]=f2bf(v0.y); o[2]=f2bf(v0.z); o[3]=f2bf(v0.w);
    o[4]=f2bf(v1.x); o[5]=f2bf(v1.y); o[6]=f2bf(v1.z); o[7]=f2bf(v1.w);
    *(bf16x8*)(out + (size_t)i * 8) = *(bf16x8*)o;
}

__global__ __launch_bounds__(256) void cast_w(const float* __restrict__ w1l,
                                              const float* __restrict__ w1r,
                                              const float* __restrict__ w2l,
                                              const float* __restrict__ w2r,
                                              u16* __restrict__ out) {
    int i = blockIdx.x * 256 + threadIdx.x;   // 65536 threads
    int mat = i >> 14, idx = i & 16383;
    const float* s = (mat == 0) ? w1l : (mat == 1) ? w1r : (mat == 2) ? w2l : w2r;
    out[i] = f2bf(s[idx]);
}

// ---------------- Aggregation: wave/node, 8-wide MLP, bf16 in/out ----------------

__global__ __launch_bounds__(256) void agg_bf16(
    const u16* __restrict__ xin, const int* __restrict__ csr,
    const int* __restrict__ rowstart, const int* __restrict__ deg,
    u16* __restrict__ mout)
{
    int w = (blockIdx.x * blockDim.x + threadIdx.x) >> 6;
    if (w >= N_NODES) return;
    int lane = threadIdx.x & 63;
    int beg = __builtin_amdgcn_readfirstlane(rowstart[w]);
    int d   = __builtin_amdgcn_readfirstlane(deg[w]);
    const u16* base = xin + (lane << 1);    // 2 bf16 (4B) per lane, row=256B

    float ax[8], ay[8];
#pragma unroll
    for (int u = 0; u < 8; ++u) { ax[u] = 0.f; ay[u] = 0.f; }

    int i = 0;
    for (; i + 8 <= d; i += 8) {
        int s[8];
#pragma unroll
        for (int u = 0; u < 8; ++u) s[u] = csr[beg + i + u];
#pragma unroll
        for (int u = 0; u < 8; ++u) {
            u32 v = *(const u32*)(base + ((size_t)s[u] << 7));
            ax[u] += __uint_as_float(v << 16);
            ay[u] += __uint_as_float(v & 0xffff0000u);
        }
    }
    if (i < d) {
        int cnt = d - i;  // 1..7, wave-uniform
        int s[8];
#pragma unroll
        for (int u = 0; u < 8; ++u) s[u] = csr[beg + i + ((u < cnt) ? u : 0)];
#pragma unroll
        for (int u = 0; u < 8; ++u) {
            u32 v = *(const u32*)(base + ((size_t)s[u] << 7));
            if (u < cnt) {
                ax[u] += __uint_as_float(v << 16);
                ay[u] += __uint_as_float(v & 0xffff0000u);
            }
        }
    }

#pragma unroll
    for (int u = 0; u < 4; ++u) { ax[u] += ax[u + 4]; ay[u] += ay[u + 4]; }
    ax[0] += ax[2]; ay[0] += ay[2];
    ax[1] += ax[3]; ay[1] += ay[3];
    ax[0] += ax[1]; ay[0] += ay[1];

    float inv = 1.f / (float)(d > 0 ? d : 1);
    u32 packed = (u32)f2bf(ax[0] * inv) | ((u32)f2bf(ay[0] * inv) << 16);
    *(u32*)(mout + ((size_t)w << 7) + (lane << 1)) = packed;
}

// ---------------- MFMA dual-GEMM: out = act(A@Wl.T + bl + X@Wr.T) ----------------
// No LDS. 4 waves/block, wave = 16 rows x 128 cols (8 col-tiles of 16).
// mfma_f32_16x16x32_bf16: A lane l holds In[m0+(l&15)][k0*32+(l>>4)*8+j] (16B contig);
// B lane l holds W[n0+(l&15)][k0*32+(l>>4)*8+j] (16B contig, since B[k][n]=W[n][k]).
// C/D (m89-verified): col=lane&15, row=(lane>>4)*4+reg.
// Safe for in-place X==out (bf16 mode): each wave reads only its own 16 rows
// (all loads issued before stores; other blocks never touch these rows).

__global__ __launch_bounds__(256) void gemm_mfma(
    const u16* __restrict__ Ab, const u16* __restrict__ Xb,
    const u16* __restrict__ Wlb, const float* __restrict__ bl,
    const u16* __restrict__ Wrb, void* __restrict__ outp, int relu_bf16)
{
    const int wv = threadIdx.x >> 6;
    const int l  = threadIdx.x & 63;
    const int m0 = blockIdx.x * 64 + wv * 16;
    const int lr = l & 15;          // A-row / B-col / D-col within tile
    const int lq = l >> 4;          // 0..3 (k-slice / D-row group)

    int arow = m0 + lr;
    if (arow > N_NODES - 1) arow = N_NODES - 1;   // clamp loads; stores masked
    const u16* abase = Ab + (size_t)arow * H + lq * 8;
    const u16* xbase = Xb + (size_t)arow * H + lq * 8;
    const u16* wlbase = Wlb + (size_t)lr * H + lq * 8;
    const u16* wrbase = Wrb + (size_t)lr * H + lq * 8;

    f32x4 acc[8];
#pragma unroll
    for (int t = 0; t < 8; ++t) acc[t] = (f32x4)0.f;

#pragma unroll
    for (int k0 = 0; k0 < 4; ++k0) {
        bf16x8 af = *(const bf16x8*)(abase + k0 * 32);
        bf16x8 xf = *(const bf16x8*)(xbase + k0 * 32);
#pragma unroll
        for (int t = 0; t < 8; ++t) {
            bf16x8 wl = *(const bf16x8*)(wlbase + (size_t)t * 16 * H + k0 * 32);
            bf16x8 wr = *(const bf16x8*)(wrbase + (size_t)t * 16 * H + k0 * 32);
            acc[t] = __builtin_amdgcn_mfma_f32_16x16x32_bf16(af, wl, acc[t], 0, 0, 0);
            acc[t] = __builtin_amdgcn_mfma_f32_16x16x32_bf16(xf, wr, acc[t], 0, 0, 0);
        }
    }

    u16* outb = (u16*)outp;
    float* outf = (float*)outp;
#pragma unroll
    for (int t = 0; t < 8; ++t) {
        int n = t * 16 + lr;
        float bv = bl[n];
#pragma unroll
        for (int r = 0; r < 4; ++r) {
            int m = m0 + lq * 4 + r;
            if (m < N_NODES) {
                float v = acc[t][r] + bv;
                if (relu_bf16) {
                    outb[(size_t)m * H + n] = f2bf(fmaxf(v, 0.f));
                } else {
                    outf[(size_t)m * H + n] = v;
                }
            }
        }
    }
}

// ---------------- launch ----------------

extern "C" void kernel_launch(void* const* d_in, const int* in_sizes, int n_in,
                              void* d_out, int out_size, void* d_ws, size_t ws_size,
                              hipStream_t stream) {
    const float* x   = (const float*)d_in[0];
    const int*   ei  = (const int*)d_in[1];
    const float* W1l = (const float*)d_in[2];
    const float* b1l = (const float*)d_in[3];
    const float* W1r = (const float*)d_in[4];
    const float* W2l = (const float*)d_in[5];
    const float* b2l = (const float*)d_in[6];
    const float* W2r = (const float*)d_in[7];

    const int* src = ei;             // edge_index[0]
    const int* dst = ei + N_EDGES;   // edge_index[1]

    // workspace layout (58.8 MB total)
    u16* xb       = (u16*)d_ws;                          // N*H bf16 (25.6MB); becomes h1b after gemm1
    u16* mb       = xb + (size_t)N_NODES * H;            // N*H bf16 (25.6MB)
    int* deg      = (int*)(mb + (size_t)N_NODES * H);    // N
    int* rowstart = deg + N_NODES;                       // N
    int* cursor   = rowstart + N_NODES;                  // N (dead after fill_csr -> holds bf16 weights)
    int* csr      = cursor + N_NODES;                    // E
    int* bsums    = csr + N_EDGES;                       // 128
    int* boffs    = bsums + 128;                         // 128
    u16* Wb       = (u16*)cursor;                        // 4 x 128*128 bf16 = 128KB (< 400KB)
    u16* W1lb = Wb;
    u16* W1rb = Wb + 16384;
    u16* W2lb = Wb + 32768;
    u16* W2rb = Wb + 49152;

    const int nb = (N_NODES + 1023) / 1024;  // 98 scan blocks

    // CSR build
    zero_ints<<<(3 * N_NODES + 255) / 256, 256, 0, stream>>>(deg, 3 * N_NODES);
    count_deg<<<(N_EDGES + 255) / 256, 256, 0, stream>>>(dst, deg, N_EDGES);
    scan_blocks<<<nb, 1024, 0, stream>>>(deg, rowstart, bsums, N_NODES);
    scan_sums<<<1, 128, 0, stream>>>(bsums, boffs, nb);
    add_offsets<<<(N_NODES + 255) / 256, 256, 0, stream>>>(rowstart, boffs, N_NODES);
    // Pre-touch csr so fill_csr's random 4B stores hit resident L2 lines and
    // merge in-cache (R6 profile: 107MB WRITE_SIZE = 64B partial-line HBM
    // writes per scatter store). Coalesced zeroing costs ~2-3us.
    zero_ints<<<(N_EDGES + 255) / 256, 256, 0, stream>>>(csr, N_EDGES);
    fill_csr<<<(N_EDGES + 255) / 256, 256, 0, stream>>>(src, dst, rowstart, cursor, csr, N_EDGES);

    // precasts (cast_w AFTER fill_csr: reuses cursor region)
    cast_w<<<65536 / 256, 256, 0, stream>>>(W1l, W1r, W2l, W2r, Wb);
    cast_x<<<(N_NODES * H / 8) / 256, 256, 0, stream>>>(x, xb);

    const int gemm_grid = (N_NODES + 63) / 64;

    // layer 1
    agg_bf16<<<(N_NODES + 3) / 4, 256, 0, stream>>>(xb, csr, rowstart, deg, mb);
    gemm_mfma<<<gemm_grid, 256, 0, stream>>>(mb, xb, W1lb, b1l, W1rb, xb, 1);  // h1b in-place over xb

    // layer 2
    agg_bf16<<<(N_NODES + 3) / 4, 256, 0, stream>>>(xb, csr, rowstart, deg, mb);
    gemm_mfma<<<gemm_grid, 256, 0, stream>>>(mb, xb, W2lb, b2l, W2rb, d_out, 0);
}

// Round 9
// 369.282 us; speedup vs baseline: 1.9437x; 1.2011x over previous
//
#include <hip/hip_runtime.h>

#define N_NODES 100000
#define N_EDGES 1600000
#define H 128

#define NB 391        // dst buckets of 256 nodes: ceil(100000/256)
#define P1_EPB 4096   // edges per pass-1 block
#define P1_BLOCKS ((N_EDGES + P1_EPB - 1) / P1_EPB)   // 391
#define P2_CAP 6144   // bucket capacity (mean 4096, sigma~64)

typedef unsigned short u16;
typedef unsigned int u32;
typedef short bf16x8 __attribute__((ext_vector_type(8)));
typedef float f32x4 __attribute__((ext_vector_type(4)));

static __device__ __forceinline__ u16 f2bf(float f) {  // RNE float->bf16
    u32 u = __float_as_uint(f);
    u += 0x7fffu + ((u >> 16) & 1u);
    return (u16)(u >> 16);
}

// ---------------- CSR build ----------------

__global__ void zero_ints(int* __restrict__ p, int n) {
    int i = blockIdx.x * blockDim.x + threadIdx.x;
    if (i < n) p[i] = 0;
}

__global__ void count_deg(const int* __restrict__ dst, int* __restrict__ deg, int e) {
    int i = blockIdx.x * blockDim.x + threadIdx.x;
    if (i < e) atomicAdd(&deg[dst[i]], 1);
}

__global__ void scan_blocks(const int* __restrict__ deg, int* __restrict__ rowstart,
                            int* __restrict__ bsums, int n) {
    __shared__ int s[1024];
    int t = threadIdx.x;
    int i = blockIdx.x * 1024 + t;
    int v = (i < n) ? deg[i] : 0;
    s[t] = v;
    __syncthreads();
    for (int off = 1; off < 1024; off <<= 1) {
        int add = (t >= off) ? s[t - off] : 0;
        __syncthreads();
        s[t] += add;
        __syncthreads();
    }
    if (i < n) rowstart[i] = s[t] - v;   // exclusive
    if (t == 1023) bsums[blockIdx.x] = s[t];
}

__global__ void scan_sums(const int* __restrict__ bsums, int* __restrict__ boffs, int nb) {
    __shared__ int s[128];
    int t = threadIdx.x;
    int v = (t < nb) ? bsums[t] : 0;
    s[t] = v;
    __syncthreads();
    for (int off = 1; off < 128; off <<= 1) {
        int add = (t >= off) ? s[t - off] : 0;
        __syncthreads();
        s[t] += add;
        __syncthreads();
    }
    if (t < nb) boffs[t] = s[t] - v;     // exclusive
}

__global__ void add_offsets(int* __restrict__ rowstart, const int* __restrict__ boffs, int n) {
    int i = blockIdx.x * blockDim.x + threadIdx.x;
    if (i < n) rowstart[i] += boffs[i >> 10];
}

__global__ void init_bcur(const int* __restrict__ rowstart, int* __restrict__ bcur) {
    int b = blockIdx.x * 256 + threadIdx.x;
    if (b < NB) bcur[b] = rowstart[b << 8];
}

// Pass 1: bin edges by dst>>8 into bucket-contiguous csr ranges (packed u32:
// bits[24:17]=dst&255, bits[16:0]=src). LDS-staged so global writes are
// slot-ordered bucket runs (R6/R7 lesson: raw 4B scatter = 64B partial-line
// HBM writebacks, 107MB for a 6.4MB array, ~105us; XCD L2s can't merge).
__global__ __launch_bounds__(1024) void p1_bin(
    const int* __restrict__ src, const int* __restrict__ dst,
    int* __restrict__ bcur, u32* __restrict__ csrp)
{
    __shared__ int s_cnt[NB];      // histogram, then running local cursor
    __shared__ int s_lstart[NB];   // block-local exclusive start per bucket
    __shared__ int s_gbase[NB];    // reserved global base per bucket
    __shared__ int s_scan[512];
    __shared__ u32 s_val[P1_EPB];
    __shared__ u32 s_gaddr[P1_EPB];

    const int t = threadIdx.x;
    const int e0 = blockIdx.x * P1_EPB;
    const int ecnt = min(P1_EPB, N_EDGES - e0);

    for (int i = t; i < NB; i += 1024) s_cnt[i] = 0;
    __syncthreads();
    for (int i = t; i < ecnt; i += 1024)
        atomicAdd(&s_cnt[dst[e0 + i] >> 8], 1);
    __syncthreads();

    int v = (t < NB) ? s_cnt[t] : 0;
    if (t < 512) s_scan[t] = v;
    __syncthreads();
    for (int off = 1; off < 512; off <<= 1) {
        int add = (t < 512 && t >= off) ? s_scan[t - off] : 0;
        __syncthreads();
        if (t < 512) s_scan[t] += add;
        __syncthreads();
    }
    if (t < NB) {
        int ls = s_scan[t] - v;   // exclusive
        s_lstart[t] = ls;
        s_gbase[t] = (v > 0) ? atomicAdd(&bcur[t], v) : 0;
        s_cnt[t] = ls;            // becomes running cursor
    }
    __syncthreads();

    for (int i = t; i < ecnt; i += 1024) {
        int d = dst[e0 + i];
        int s = src[e0 + i];
        int b = d >> 8;
        int slot = atomicAdd(&s_cnt[b], 1);
        s_val[slot]   = ((u32)(d & 255) << 17) | (u32)s;
        s_gaddr[slot] = (u32)(s_gbase[b] + (slot - s_lstart[b]));
    }
    __syncthreads();
    for (int i = t; i < ecnt; i += 1024)
        csrp[s_gaddr[i]] = s_val[i];
}

// Pass 2: one block per bucket; bin packed entries to exact per-node order in
// LDS, write back fully coalesced. In-place safe (load barrier store).
__global__ __launch_bounds__(1024) void p2_scatter(
    const int* __restrict__ rowstart, int* __restrict__ csr)
{
    __shared__ int s_cur[256];
    __shared__ u32 s_out[P2_CAP];
    const int b = blockIdx.x;
    const int t = threadIdx.x;
    const int n0 = b << 8;
    const int s0 = rowstart[n0];
    const int s1 = (b == NB - 1) ? N_EDGES : rowstart[n0 + 256];
    const int cnt = s1 - s0;

    if (t < 256) {
        int node = n0 + t;
        s_cur[t] = (node < N_NODES) ? (rowstart[node] - s0) : cnt;
    }
    __syncthreads();
    for (int i = t; i < cnt; i += 1024) {
        u32 p = (u32)csr[s0 + i];
        int pos = atomicAdd(&s_cur[p >> 17], 1);
        s_out[pos] = p & 0x1FFFFu;
    }
    __syncthreads();
    for (int i = t; i < cnt; i += 1024)
        csr[s0 + i] = (int)s_out[i];
}

// ---------------- casts ----------------

__global__ __launch_bounds__(256) void cast_x(const float* __restrict__ in,
                                              u16* __restrict__ out) {
    int i = blockIdx.x * 256 + threadIdx.x;   // 1.6M threads x 8 elems
    const float4 v0 = *(const float4*)(in + (size_t)i * 8);
    const float4 v1 = *(const float4*)(in + (size_t)i * 8 + 4);
    u16 o[8];
    o[0]=f2bf(v0.x); o[1]=f2bf(v0.y); o[2]=f2bf(v0.z); o[3]=f2bf(v0.w);
    o[4]=f2bf(v1.x); o[5]=f2bf(v1.y); o[6]=f2bf(v1.z); o[7]=f2bf(v1.w);
    *(bf16x8*)(out + (size_t)i * 8) = *(bf16x8*)o;
}

__global__ __launch_bounds__(256) void cast_w(const float* __restrict__ w1l,
                                              const float* __restrict__ w1r,
                                              const float* __restrict__ w2l,
                                              const float* __restrict__ w2r,
                                              u16* __restrict__ out) {
    int i = blockIdx.x * 256 + threadIdx.x;   // 65536 threads
    int mat = i >> 14, idx = i & 16383;
    const float* s = (mat == 0) ? w1l : (mat == 1) ? w1r : (mat == 2) ? w2l : w2r;
    out[i] = f2bf(s[idx]);
}

// ---------------- Aggregation: wave/node, 8-wide MLP, bf16 in/out ----------------

__global__ __launch_bounds__(256) void agg_bf16(
    const u16* __restrict__ xin, const int* __restrict__ csr,
    const int* __restrict__ rowstart, const int* __restrict__ deg,
    u16* __restrict__ mout)
{
    int w = (blockIdx.x * blockDim.x + threadIdx.x) >> 6;
    if (w >= N_NODES) return;
    int lane = threadIdx.x & 63;
    int beg = __builtin_amdgcn_readfirstlane(rowstart[w]);
    int d   = __builtin_amdgcn_readfirstlane(deg[w]);
    const u16* base = xin + (lane << 1);    // 2 bf16 (4B) per lane, row=256B

    float ax[8], ay[8];
#pragma unroll
    for (int u = 0; u < 8; ++u) { ax[u] = 0.f; ay[u] = 0.f; }

    int i = 0;
    for (; i + 8 <= d; i += 8) {
        int s[8];
#pragma unroll
        for (int u = 0; u < 8; ++u) s[u] = csr[beg + i + u];
#pragma unroll
        for (int u = 0; u < 8; ++u) {
            u32 v = *(const u32*)(base + ((size_t)s[u] << 7));
            ax[u] += __uint_as_float(v << 16);
            ay[u] += __uint_as_float(v & 0xffff0000u);
        }
    }
    if (i < d) {
        int cnt = d - i;  // 1..7, wave-uniform
        int s[8];
#pragma unroll
        for (int u = 0; u < 8; ++u) s[u] = csr[beg + i + ((u < cnt) ? u : 0)];
#pragma unroll
        for (int u = 0; u < 8; ++u) {
            u32 v = *(const u32*)(base + ((size_t)s[u] << 7));
            if (u < cnt) {
                ax[u] += __uint_as_float(v << 16);
                ay[u] += __uint_as_float(v & 0xffff0000u);
            }
        }
    }

#pragma unroll
    for (int u = 0; u < 4; ++u) { ax[u] += ax[u + 4]; ay[u] += ay[u + 4]; }
    ax[0] += ax[2]; ay[0] += ay[2];
    ax[1] += ax[3]; ay[1] += ay[3];
    ax[0] += ax[1]; ay[0] += ay[1];

    float inv = 1.f / (float)(d > 0 ? d : 1);
    u32 packed = (u32)f2bf(ax[0] * inv) | ((u32)f2bf(ay[0] * inv) << 16);
    *(u32*)(mout + ((size_t)w << 7) + (lane << 1)) = packed;
}

// ---------------- MFMA dual-GEMM: out = act(A@Wl.T + bl + X@Wr.T) ----------------
// No LDS. 4 waves/block, wave = 16 rows x 128 cols (8 col-tiles of 16).
// C/D (m89-verified): col=lane&15, row=(lane>>4)*4+reg.

__global__ __launch_bounds__(256) void gemm_mfma(
    const u16* __restrict__ Ab, const u16* __restrict__ Xb,
    const u16* __restrict__ Wlb, const float* __restrict__ bl,
    const u16* __restrict__ Wrb, void* __restrict__ outp, int relu_bf16)
{
    const int wv = threadIdx.x >> 6;
    const int l  = threadIdx.x & 63;
    const int m0 = blockIdx.x * 64 + wv * 16;
    const int lr = l & 15;          // A-row / B-col / D-col within tile
    const int lq = l >> 4;          // 0..3 (k-slice / D-row group)

    int arow = m0 + lr;
    if (arow > N_NODES - 1) arow = N_NODES - 1;   // clamp loads; stores masked
    const u16* abase = Ab + (size_t)arow * H + lq * 8;
    const u16* xbase = Xb + (size_t)arow * H + lq * 8;
    const u16* wlbase = Wlb + (size_t)lr * H + lq * 8;
    const u16* wrbase = Wrb + (size_t)lr * H + lq * 8;

    f32x4 acc[8];
#pragma unroll
    for (int t = 0; t < 8; ++t) acc[t] = (f32x4)0.f;

#pragma unroll
    for (int k0 = 0; k0 < 4; ++k0) {
        bf16x8 af = *(const bf16x8*)(abase + k0 * 32);
        bf16x8 xf = *(const bf16x8*)(xbase + k0 * 32);
#pragma unroll
        for (int t = 0; t < 8; ++t) {
            bf16x8 wl = *(const bf16x8*)(wlbase + (size_t)t * 16 * H + k0 * 32);
            bf16x8 wr = *(const bf16x8*)(wrbase + (size_t)t * 16 * H + k0 * 32);
            acc[t] = __builtin_amdgcn_mfma_f32_16x16x32_bf16(af, wl, acc[t], 0, 0, 0);
            acc[t] = __builtin_amdgcn_mfma_f32_16x16x32_bf16(xf, wr, acc[t], 0, 0, 0);
        }
    }

    u16* outb = (u16*)outp;
    float* outf = (float*)outp;
#pragma unroll
    for (int t = 0; t < 8; ++t) {
        int n = t * 16 + lr;
        float bv = bl[n];
#pragma unroll
        for (int r = 0; r < 4; ++r) {
            int m = m0 + lq * 4 + r;
            if (m < N_NODES) {
                float v = acc[t][r] + bv;
                if (relu_bf16) {
                    outb[(size_t)m * H + n] = f2bf(fmaxf(v, 0.f));
                } else {
                    outf[(size_t)m * H + n] = v;
                }
            }
        }
    }
}

// ---------------- launch ----------------

extern "C" void kernel_launch(void* const* d_in, const int* in_sizes, int n_in,
                              void* d_out, int out_size, void* d_ws, size_t ws_size,
                              hipStream_t stream) {
    const float* x   = (const float*)d_in[0];
    const int*   ei  = (const int*)d_in[1];
    const float* W1l = (const float*)d_in[2];
    const float* b1l = (const float*)d_in[3];
    const float* W1r = (const float*)d_in[4];
    const float* W2l = (const float*)d_in[5];
    const float* b2l = (const float*)d_in[6];
    const float* W2r = (const float*)d_in[7];

    const int* src = ei;             // edge_index[0]
    const int* dst = ei + N_EDGES;   // edge_index[1]

    // workspace layout (~58.8 MB)
    u16* xb       = (u16*)d_ws;                          // N*H bf16; becomes h1b after gemm1
    u16* mb       = xb + (size_t)N_NODES * H;            // N*H bf16
    int* deg      = (int*)(mb + (size_t)N_NODES * H);    // N
    int* rowstart = deg + N_NODES;                       // N
    int* wslot    = rowstart + N_NODES;                  // N ints (bf16 weights home)
    int* csr      = wslot + N_NODES;                     // E
    int* bsums    = csr + N_EDGES;                       // 128
    int* boffs    = bsums + 128;                         // 128
    int* bcur     = boffs + 128;                         // NB bucket cursors
    u16* Wb       = (u16*)wslot;                         // 4 x 128*128 bf16 = 128KB
    u16* W1lb = Wb;
    u16* W1rb = Wb + 16384;
    u16* W2lb = Wb + 32768;
    u16* W2rb = Wb + 49152;

    const int nb = (N_NODES + 1023) / 1024;  // 98 scan blocks

    // CSR build: histogram -> scan -> 2-pass LDS-staged counting sort
    zero_ints<<<(N_NODES + 255) / 256, 256, 0, stream>>>(deg, N_NODES);
    count_deg<<<(N_EDGES + 255) / 256, 256, 0, stream>>>(dst, deg, N_EDGES);
    scan_blocks<<<nb, 1024, 0, stream>>>(deg, rowstart, bsums, N_NODES);
    scan_sums<<<1, 128, 0, stream>>>(bsums, boffs, nb);
    add_offsets<<<(N_NODES + 255) / 256, 256, 0, stream>>>(rowstart, boffs, N_NODES);
    init_bcur<<<(NB + 255) / 256, 256, 0, stream>>>(rowstart, bcur);
    p1_bin<<<P1_BLOCKS, 1024, 0, stream>>>(src, dst, bcur, (u32*)csr);
    p2_scatter<<<NB, 1024, 0, stream>>>(rowstart, csr);

    // precasts (cast_w reuses the dead cursor slot region)
    cast_w<<<65536 / 256, 256, 0, stream>>>(W1l, W1r, W2l, W2r, Wb);
    cast_x<<<(N_NODES * H / 8) / 256, 256, 0, stream>>>(x, xb);

    const int gemm_grid = (N_NODES + 63) / 64;

    // layer 1
    agg_bf16<<<(N_NODES + 3) / 4, 256, 0, stream>>>(xb, csr, rowstart, deg, mb);
    gemm_mfma<<<gemm_grid, 256, 0, stream>>>(mb, xb, W1lb, b1l, W1rb, xb, 1);  // h1b in-place over xb

    // layer 2
    agg_bf16<<<(N_NODES + 3) / 4, 256, 0, stream>>>(xb, csr, rowstart, deg, mb);
    gemm_mfma<<<gemm_grid, 256, 0, stream>>>(mb, xb, W2lb, b2l, W2rb, d_out, 0);
}